// Round 20
// baseline (446.718 us; speedup 1.0000x reference)
//
#include <hip/hip_runtime.h>
#include <math.h>

#define BB 64
#define HH 512
#define WW 512
#define HWQ (HH*WW)
#define NTOT ((size_t)BB*HWQ)

// ws layout:
//  [0, 2MB)   : TRANSPOSED bitmask: byte for (b, bytecol bc, row r) at
//               bitsT[((b*32 + (r>>4))*64 + bc)*16 + (r&15)]
//  then doubles:
//   [0..63]      a_c slots (k_fused atomics; zeroed by k_bitsT block 0)
//   [64+8b+0,1]  TP_b, sumP_b (k_fused atomics; zeroed by k_bitsT block 0)
//   [570]        (as bytes) completion counter for last-block final
//   [576+blk]    k_bitsT per-block t-count partials (plain stores)
#define BITS_BYTES (NTOT / 8)
#define ACC_MAIN_DOUBLES 576
#define NFBLK 4096

#define FU(X) (__float_as_uint(X))

// target f32 -> transposed bitmask + per-block t-count. 1024 blocks. (R14 proven)
__global__ __launch_bounds__(256) void k_bitsT(const float* __restrict__ tgt,
                                               unsigned char* __restrict__ bitsT,
                                               double* __restrict__ accz,
                                               double* __restrict__ tpart) {
  if (blockIdx.x == 0) {
    for (int i = threadIdx.x; i < ACC_MAIN_DOUBLES; i += 256) accz[i] = 0.0;
  }
  int tid  = threadIdx.x;
  int bc   = tid & 63;
  int unit = blockIdx.x * 4 + (tid >> 6);   // 4096 units = 64 img x 64 rowgroups(8)
  int b    = unit >> 6;
  int rg   = unit & 63;
  int r0   = rg * 8;
  const float* timg = tgt + (size_t)b * HWQ;
  unsigned wlo = 0u, whi = 0u;
#pragma unroll
  for (int j = 0; j < 8; ++j) {
    const float* rp = timg + (size_t)(r0 + j) * WW + bc * 8;
    float4 a = *(const float4*)rp;
    float4 c = *(const float4*)(rp + 4);
    unsigned by = ((FU(a.x) >> 29) & 1u)        | (((FU(a.y) >> 29) & 1u) << 1)
                | (((FU(a.z) >> 29) & 1u) << 2) | (((FU(a.w) >> 29) & 1u) << 3)
                | (((FU(c.x) >> 29) & 1u) << 4) | (((FU(c.y) >> 29) & 1u) << 5)
                | (((FU(c.z) >> 29) & 1u) << 6) | (((FU(c.w) >> 29) & 1u) << 7);
    if (j < 4) wlo |= by << (8 * j); else whi |= by << (8 * (j - 4));
  }
  int rb = r0 >> 4, off = r0 & 15;
  *(uint2*)(bitsT + (((size_t)(b * 32 + rb) * 64 + bc) << 4) + off) = make_uint2(wlo, whi);

  int cnt = __popc(wlo) + __popc(whi);
#pragma unroll
  for (int o = 32; o > 0; o >>= 1) cnt += __shfl_down(cnt, o, 64);
  __shared__ int s_t[4];
  int wv = tid >> 6, lane = tid & 63;
  if (lane == 0) s_t[wv] = cnt;
  __syncthreads();
  if (tid == 0) tpart[blockIdx.x] = (double)(s_t[0] + s_t[1] + s_t[2] + s_t[3]);
}

// nibble -> byte-lane spread (bit j of nibble -> byte j)
#define SPL(B) ((((B) & 0xFu) * 0x00204081u) & 0x01010101u)
#define SPH(B) ((((B) >> 4)   * 0x00204081u) & 0x01010101u)

// byte K (0..47) of the 3-block register window B0,B1,B2 (K compile-time)
#define W48(K) ((K)<16 ? (((K)&15)<8 ? (((K)&15)<4?B0.x:B0.y) : (((K)&15)<12?B0.z:B0.w)) \
              : (K)<32 ? (((K)&15)<8 ? (((K)&15)<4?B1.x:B1.y) : (((K)&15)<12?B1.z:B1.w)) \
                       : (((K)&15)<8 ? (((K)&15)<4?B2.x:B2.y) : (((K)&15)<12?B2.z:B2.w)))
#define BYTE48(K) ((W48(K) >> (((K)&3)*8)) & 0xFFu)

__device__ inline float wredf(float v) {
#pragma unroll
  for (int o = 32; o > 0; o >>= 1) v += __shfl_down(v, o, 64);
  return v;
}

__device__ inline int sum4b(unsigned x) {     // sum of the 4 bytes
  unsigned t = (x & 0x00FF00FFu) + ((x >> 8) & 0x00FF00FFu);
  return (int)((t + (t >> 16)) & 0xFFFFu);
}

// window byte I (0..39) <-> col x0-16+I ; I compile-time -> folds to one bfe
#define VTW(I) ((I) < 8  ? (((I)&7) < 4 ? c0x : c0y) : \
                (I) < 16 ? (((I)&7) < 4 ? c1x : c1y) : \
                (I) < 24 ? (((I)&7) < 4 ? c2x : c2y) : \
                (I) < 32 ? (((I)&7) < 4 ? c3x : c3y) : \
                           (((I)&7) < 4 ? c4x : c4y))
#define BGET5(I) ((int)((VTW(I) >> (((I)&3)*8)) & 31u))   // 5-bit vsum field

// one output column (identical math to R8/R12/R15/R16/R17, which passed)
#define STEP(C, UM, UP, VM, VC, VP, TCI, PV) do {                     \
    int gx = (UP) - (UM);                                             \
    int gy = (VM) + 2*(VC) + (VP) - 4;                                \
    float tb = __builtin_amdgcn_sqrtf((float)(gx*gx + gy*gy) + 1e-12f); \
    float qq = (TCI) ? (PV) : 1.f - (PV);                             \
    float lg = __log2f(qq);                                           \
    int   di = (TCI) ? (961 - sw) : sw;                               \
    float wgt = fmaf(5.f, tb, fmaf(1.5608741e-3f, (float)di, 0.8f));  \
    a_c = fmaf(wgt, lg, a_c);                                         \
    a_pt += (TCI) ? (PV) : 0.f;                                       \
    a_p  += (PV);                                                     \
    sw += BGET5((C)+32) - BGET5((C)+1);                               \
  } while (0)

#define UB(W,J) ((int)(((W) >> (8*(J))) & 7u))            // u byte (0..4)
#define VB(W,J) ((int)(((W) >> (8*(J))) & 3u))            // v+1 byte (0..2)

#define SHFLS(DX, DY, SX, SY)                               \
    DX##1x = __shfl_up(SX, 1, 64);  DY##1y = __shfl_up(SY, 1, 64);  \
    DX##0x = __shfl_up(SX, 2, 64);  DY##0y = __shfl_up(SY, 2, 64);  \
    DX##3x = __shfl_down(SX, 1, 64); DY##3y = __shfl_down(SY, 1, 64); \
    DX##4x = __shfl_down(SX, 2, 64); DY##4y = __shfl_down(SY, 2, 64)

// fused body (2 rows), rolling SPL/SPH registers; E = ys & 15 in {0,2,...,14}.
template<int E>
__device__ __forceinline__ void fused_rows(uint4 B0, uint4 B1, uint4 B2,
                                           const float* __restrict__ prow,
                                           int lane,
                                           float& a_c, float& a_pt, float& a_p) {
  // two-chain 31-tap init
  unsigned cLoA = 0u, cHiA = 0u, cLoB = 0u, cHiB = 0u;
#pragma unroll
  for (int j = -15; j <= 13; j += 2) {
    unsigned ba_ = BYTE48(j + 16 + E);
    unsigned bb_ = BYTE48(j + 17 + E);
    cLoA += SPL(ba_); cHiA += SPH(ba_);
    cLoB += SPL(bb_); cHiB += SPH(bb_);
  }
  { unsigned bl_ = BYTE48(31 + E); cLoA += SPL(bl_); cHiA += SPH(bl_); }
  unsigned cLo = cLoA + cLoB, cHi = cHiA + cHiB;

  unsigned bm = BYTE48(15 + E);   // row ys-1 (OOB auto-zero via zeroed blocks)
  unsigned bz = BYTE48(16 + E);   // row ys
  unsigned bq = BYTE48(17 + E);   // row ys+1
  unsigned smLo = SPL(bm), smHi = SPH(bm);
  unsigned szLo = SPL(bz), szHi = SPH(bz);
  unsigned sqLo = SPL(bq), sqHi = SPH(bq);

  // row 0: packed word + shfls + pred
  unsigned w2x = cLo | (szLo << 5) | (smLo << 6) | (sqLo << 7);
  unsigned w2y = cHi | (szHi << 5) | (smHi << 6) | (sqHi << 7);
  unsigned w1x, w0x, w3x, w4x, w1y, w0y, w3y, w4y;
  SHFLS(w, w, w2x, w2y);
  float4 pA = *(const float4*)prow;
  float4 pB = *(const float4*)(prow + 4);

#pragma unroll
  for (int j = 0; j < 2; ++j) {
    // ---- current-row own derived (from rolling regs, BEFORE roll) ----
    unsigned uLo = smLo + sqLo + 2u * szLo;
    unsigned uHi = smHi + sqHi + 2u * szHi;
    unsigned vLo = (sqLo + 0x01010101u) - smLo;
    unsigned vHi = (sqHi + 0x01010101u) - smHi;
    unsigned bzCur = bz;
    unsigned cw2x = w2x, cw2y = w2y;

    // ---- prefetch next row (pred + roll + window shfls) ----
    unsigned nw2x = 0u, nw2y = 0u;
    unsigned nw1x = 0u, nw0x = 0u, nw3x = 0u, nw4x = 0u;
    unsigned nw1y = 0u, nw0y = 0u, nw3y = 0u, nw4y = 0u;
    float4 nA = make_float4(0, 0, 0, 0), nB = make_float4(0, 0, 0, 0);
    if (j < 1) {
      nA = *(const float4*)(prow + WW);
      nB = *(const float4*)(prow + WW + 4);
      unsigned ba = BYTE48(32 + E + j);   // row ys+j+16 enters box
      unsigned bs = BYTE48(1 + E + j);    // row ys+j-15 leaves box
      cLo += SPL(ba) - SPL(bs);
      cHi += SPH(ba) - SPH(bs);
      smLo = szLo; smHi = szHi; szLo = sqLo; szHi = sqHi; bz = bq;
      bq = BYTE48(18 + E + j);
      sqLo = SPL(bq); sqHi = SPH(bq);
      nw2x = cLo | (szLo << 5) | (smLo << 6) | (sqLo << 7);
      nw2y = cHi | (szHi << 5) | (smHi << 6) | (sqHi << 7);
      SHFLS(nw, nw, nw2x, nw2y);
    }

    // ---- current row: mask edges, then STEP ----
    unsigned c0x = (lane < 2)  ? 0u : w0x, c0y = (lane < 2)  ? 0u : w0y;
    unsigned c1x = (lane < 1)  ? 0u : w1x, c1y = (lane < 1)  ? 0u : w1y;
    unsigned c2x = cw2x,                   c2y = cw2y;
    unsigned c3x = (lane > 62) ? 0u : w3x, c3y = (lane > 62) ? 0u : w3y;
    unsigned c4x = (lane > 61) ? 0u : w4x, c4y = (lane > 61) ? 0u : w4y;

    int zm1 = (int)((c1y >> 29) & 1u), mm1 = (int)((c1y >> 30) & 1u), qm1 = (int)(c1y >> 31);
    int zp8 = (int)((c3x >> 5) & 1u),  mp8 = (int)((c3x >> 6) & 1u),  qp8 = (int)((c3x >> 7) & 1u);
    int uM1 = mm1 + 2*zm1 + qm1, vM1 = qm1 - mm1 + 1;
    int uP8 = mp8 + 2*zp8 + qp8, vP8 = qp8 - mp8 + 1;

    int u0=UB(uLo,0), u1=UB(uLo,1), u2c=UB(uLo,2), u3=UB(uLo,3);
    int u4=UB(uHi,0), u5=UB(uHi,1), u6=UB(uHi,2), u7=UB(uHi,3);
    int v0=VB(vLo,0), v1=VB(vLo,1), v2c=VB(vLo,2), v3=VB(vLo,3);
    int v4=VB(vHi,0), v5=VB(vHi,1), v6=VB(vHi,2), v7=VB(vHi,3);
    int t0=(int)((bzCur>>0)&1u), t1=(int)((bzCur>>1)&1u), t2=(int)((bzCur>>2)&1u), t3=(int)((bzCur>>3)&1u);
    int t4=(int)((bzCur>>4)&1u), t5=(int)((bzCur>>5)&1u), t6=(int)((bzCur>>6)&1u), t7=(int)((bzCur>>7)&1u);

    unsigned p0 = (c0x & 0x1F1F1F1Fu) + (c0y & 0x1F1F1F1Fu)
                + (c1x & 0x1F1F1F1Fu) + (c1y & 0x1F1F1F1Fu)
                + (c2x & 0x1F1F1F1Fu) + (c2y & 0x1F1F1F1Fu)
                + (c3x & 0x1F1F1F1Fu) + (c3y & 0x1F1F1F1Fu);
    int sw = sum4b(p0) - (int)(c0x & 0x1Fu);

    STEP(0, uM1, u1,  vM1, v0,  v1,  t0, pA.x);
    STEP(1, u0,  u2c, v0,  v1,  v2c, t1, pA.y);
    STEP(2, u1,  u3,  v1,  v2c, v3,  t2, pA.z);
    STEP(3, u2c, u4,  v2c, v3,  v4,  t3, pA.w);
    STEP(4, u3,  u5,  v3,  v4,  v5,  t4, pB.x);
    STEP(5, u4,  u6,  v4,  v5,  v6,  t5, pB.y);
    STEP(6, u5,  u7,  v5,  v6,  v7,  t6, pB.z);
    STEP(7, u6,  uP8, v6,  v7,  vP8, t7, pB.w);

    // ---- rotate pipeline ----
    w2x = nw2x; w2y = nw2y;
    w0x = nw0x; w0y = nw0y; w1x = nw1x; w1y = nw1y;
    w3x = nw3x; w3y = nw3y; w4x = nw4x; w4y = nw4y;
    pA = nA; pB = nB;
    prow += WW;
  }
}

// fully fused: wave = 64 byte-cols x 2 rows (4096 blocks -> max TLP);
// last block performs the final reduction (atomic-counter pattern).
__global__ __launch_bounds__(256) void k_fused(const float* __restrict__ pred,
                                               const unsigned char* __restrict__ bitsT,
                                               double* __restrict__ acc,
                                               const double* __restrict__ tpart,
                                               float* __restrict__ out) {
  __shared__ float s_red[4][3];
  __shared__ unsigned s_done;
  // XCD grouping: XCD x (= blockIdx%8) handles wids x*512..x*512+511 = 8 images
  int wid = (blockIdx.x & 7) * 512 + (blockIdx.x >> 3);   // bijective, 4096 blocks
  int b   = wid >> 6;
  int tid = threadIdx.x;
  int wv  = tid >> 6, lane = tid & 63;
  int ys  = (wid & 63) * 8 + wv * 2;   // wave's 2-row segment base
  int s2  = ys >> 4;                   // 16-row block index

  uint4 B0 = make_uint4(0u,0u,0u,0u), B2 = make_uint4(0u,0u,0u,0u);
  if (s2 >= 1)  B0 = *(const uint4*)(bitsT + (((size_t)(b * 32 + s2 - 1) * 64 + lane) << 4));
  uint4 B1      = *(const uint4*)(bitsT + (((size_t)(b * 32 + s2)     * 64 + lane) << 4));
  if (s2 <= 30) B2 = *(const uint4*)(bitsT + (((size_t)(b * 32 + s2 + 1) * 64 + lane) << 4));

  const float* prow = pred + (size_t)b * HWQ + (size_t)ys * WW + lane * 8;

  float a_c = 0.f, a_pt = 0.f, a_p = 0.f;
  switch ((ys >> 1) & 7) {
    case 0: fused_rows<0>(B0, B1, B2, prow, lane, a_c, a_pt, a_p);  break;
    case 1: fused_rows<2>(B0, B1, B2, prow, lane, a_c, a_pt, a_p);  break;
    case 2: fused_rows<4>(B0, B1, B2, prow, lane, a_c, a_pt, a_p);  break;
    case 3: fused_rows<6>(B0, B1, B2, prow, lane, a_c, a_pt, a_p);  break;
    case 4: fused_rows<8>(B0, B1, B2, prow, lane, a_c, a_pt, a_p);  break;
    case 5: fused_rows<10>(B0, B1, B2, prow, lane, a_c, a_pt, a_p); break;
    case 6: fused_rows<12>(B0, B1, B2, prow, lane, a_c, a_pt, a_p); break;
    default: fused_rows<14>(B0, B1, B2, prow, lane, a_c, a_pt, a_p); break;
  }

  a_c = wredf(a_c); a_pt = wredf(a_pt); a_p = wredf(a_p);
  if (lane == 0) { s_red[wv][0] = a_c; s_red[wv][1] = a_pt; s_red[wv][2] = a_p; }
  __syncthreads();
  if (tid == 0) {
    float rc = 0, rpt = 0, rp = 0;
    for (int w = 0; w < 4; ++w) { rc += s_red[w][0]; rpt += s_red[w][1]; rp += s_red[w][2]; }
    atomicAdd(&acc[wid & 63],     (double)rc);
    atomicAdd(&acc[64 + 8*b + 0], (double)rpt);
    atomicAdd(&acc[64 + 8*b + 1], (double)rp);
  }

  // ---- last-block final reduction ----
  __threadfence();
  if (tid == 0) {
    unsigned* cnt = (unsigned*)&acc[570];
    s_done = (atomicAdd(cnt, 1u) == NFBLK - 1) ? 1u : 0u;
  }
  __syncthreads();
  if (s_done && tid < 64) {
    __threadfence();
    int t = tid;   // image index
    double cs = atomicAdd(&acc[t], 0.0);                 // atomic read: XCD-coherent
    double TP = atomicAdd(&acc[64 + 8*t], 0.0);
    double Ps = atomicAdd(&acc[64 + 8*t + 1], 0.0);
    double Ts = 0.0;
    for (int j = 0; j < 16; ++j) Ts += tpart[t * 16 + j]; // written pre-kernel-boundary
    double FP = Ps - TP, FN = Ts - TP;
    double tv = (TP + 1e-6) / (TP + 0.3 * FP + 0.7 * FN + 1e-6);
    double om = 1.0 - tv;
    if (om < 0.0) om = 0.0;
    double term = pow(om, 1.0 / 1.33);
#pragma unroll
    for (int o = 32; o > 0; o >>= 1) {
      cs   += __shfl_down(cs, o, 64);
      term += __shfl_down(term, o, 64);
    }
    if (t == 0) {
      double ftl = term / 64.0;
      double n = (double)NTOT;
      out[0] = (float)(ftl - 0.6931471805599453 * cs / n);  // bce = -ln2 * log2(q)
    }
  }
}

extern "C" void kernel_launch(void* const* d_in, const int* in_sizes, int n_in,
                              void* d_out, int out_size, void* d_ws, size_t ws_size,
                              hipStream_t stream) {
  (void)in_sizes; (void)n_in; (void)out_size; (void)ws_size;
  const float* pred = (const float*)d_in[0];
  const float* tgt  = (const float*)d_in[1];
  unsigned char* bitsT = (unsigned char*)d_ws;
  double* acc = (double*)((char*)d_ws + BITS_BYTES);
  double* tpart = acc + ACC_MAIN_DOUBLES;

  k_bitsT<<<1024, 256, 0, stream>>>(tgt, bitsT, acc, tpart);
  k_fused<<<NFBLK, 256, 0, stream>>>(pred, bitsT, acc, tpart, (float*)d_out);
}

// Round 21
// 45.551 us; speedup vs baseline: 9.8069x; 9.8069x over previous
//
#include <hip/hip_runtime.h>
#include <math.h>

#define BB 64
#define HH 512
#define WW 512
#define HWQ (HH*WW)
#define NTOT ((size_t)BB*HWQ)

// ws layout:
//  [0, 2MB)   : TRANSPOSED bitmask: byte for (b, bytecol bc, row r) at
//               bitsT[((b*32 + (r>>4))*64 + bc)*16 + (r&15)]
//  then doubles:
//   [0..63]      a_c slots (k_fused atomics; zeroed by k_bitsT block 0)
//   [64+8b+0,1]  TP_b, sumP_b (k_fused atomics; zeroed by k_bitsT block 0)
//   [576+blk]    k_bitsT per-block t-count partials (plain stores)
#define BITS_BYTES (NTOT / 8)
#define ACC_MAIN_DOUBLES 576
#define NFBLK 4096

#define FU(X) (__float_as_uint(X))

// target f32 -> transposed bitmask + per-block t-count. 1024 blocks. (R14 proven)
__global__ __launch_bounds__(256) void k_bitsT(const float* __restrict__ tgt,
                                               unsigned char* __restrict__ bitsT,
                                               double* __restrict__ accz,
                                               double* __restrict__ tpart) {
  if (blockIdx.x == 0) {
    for (int i = threadIdx.x; i < ACC_MAIN_DOUBLES; i += 256) accz[i] = 0.0;
  }
  int tid  = threadIdx.x;
  int bc   = tid & 63;
  int unit = blockIdx.x * 4 + (tid >> 6);   // 4096 units = 64 img x 64 rowgroups(8)
  int b    = unit >> 6;
  int rg   = unit & 63;
  int r0   = rg * 8;
  const float* timg = tgt + (size_t)b * HWQ;
  unsigned wlo = 0u, whi = 0u;
#pragma unroll
  for (int j = 0; j < 8; ++j) {
    const float* rp = timg + (size_t)(r0 + j) * WW + bc * 8;
    float4 a = *(const float4*)rp;
    float4 c = *(const float4*)(rp + 4);
    unsigned by = ((FU(a.x) >> 29) & 1u)        | (((FU(a.y) >> 29) & 1u) << 1)
                | (((FU(a.z) >> 29) & 1u) << 2) | (((FU(a.w) >> 29) & 1u) << 3)
                | (((FU(c.x) >> 29) & 1u) << 4) | (((FU(c.y) >> 29) & 1u) << 5)
                | (((FU(c.z) >> 29) & 1u) << 6) | (((FU(c.w) >> 29) & 1u) << 7);
    if (j < 4) wlo |= by << (8 * j); else whi |= by << (8 * (j - 4));
  }
  int rb = r0 >> 4, off = r0 & 15;
  *(uint2*)(bitsT + (((size_t)(b * 32 + rb) * 64 + bc) << 4) + off) = make_uint2(wlo, whi);

  int cnt = __popc(wlo) + __popc(whi);
#pragma unroll
  for (int o = 32; o > 0; o >>= 1) cnt += __shfl_down(cnt, o, 64);
  __shared__ int s_t[4];
  int wv = tid >> 6, lane = tid & 63;
  if (lane == 0) s_t[wv] = cnt;
  __syncthreads();
  if (tid == 0) tpart[blockIdx.x] = (double)(s_t[0] + s_t[1] + s_t[2] + s_t[3]);
}

// nibble -> byte-lane spread (bit j of nibble -> byte j)
#define SPL(B) ((((B) & 0xFu) * 0x00204081u) & 0x01010101u)
#define SPH(B) ((((B) >> 4)   * 0x00204081u) & 0x01010101u)

// byte K (0..47) of the 3-block register window B0,B1,B2 (K compile-time)
#define W48(K) ((K)<16 ? (((K)&15)<8 ? (((K)&15)<4?B0.x:B0.y) : (((K)&15)<12?B0.z:B0.w)) \
              : (K)<32 ? (((K)&15)<8 ? (((K)&15)<4?B1.x:B1.y) : (((K)&15)<12?B1.z:B1.w)) \
                       : (((K)&15)<8 ? (((K)&15)<4?B2.x:B2.y) : (((K)&15)<12?B2.z:B2.w)))
#define BYTE48(K) ((W48(K) >> (((K)&3)*8)) & 0xFFu)

__device__ inline float wredf(float v) {
#pragma unroll
  for (int o = 32; o > 0; o >>= 1) v += __shfl_down(v, o, 64);
  return v;
}

__device__ inline int sum4b(unsigned x) {     // sum of the 4 bytes
  unsigned t = (x & 0x00FF00FFu) + ((x >> 8) & 0x00FF00FFu);
  return (int)((t + (t >> 16)) & 0xFFFFu);
}

// window byte I (0..39) <-> col x0-16+I ; I compile-time -> folds to one bfe
#define VTW(I) ((I) < 8  ? (((I)&7) < 4 ? c0x : c0y) : \
                (I) < 16 ? (((I)&7) < 4 ? c1x : c1y) : \
                (I) < 24 ? (((I)&7) < 4 ? c2x : c2y) : \
                (I) < 32 ? (((I)&7) < 4 ? c3x : c3y) : \
                           (((I)&7) < 4 ? c4x : c4y))
#define BGET5(I) ((int)((VTW(I) >> (((I)&3)*8)) & 31u))   // 5-bit vsum field

// one output column (identical math to R8/R12/R15/R16/R17, which passed)
#define STEP(C, UM, UP, VM, VC, VP, TCI, PV) do {                     \
    int gx = (UP) - (UM);                                             \
    int gy = (VM) + 2*(VC) + (VP) - 4;                                \
    float tb = __builtin_amdgcn_sqrtf((float)(gx*gx + gy*gy) + 1e-12f); \
    float qq = (TCI) ? (PV) : 1.f - (PV);                             \
    float lg = __log2f(qq);                                           \
    int   di = (TCI) ? (961 - sw) : sw;                               \
    float wgt = fmaf(5.f, tb, fmaf(1.5608741e-3f, (float)di, 0.8f));  \
    a_c = fmaf(wgt, lg, a_c);                                         \
    a_pt += (TCI) ? (PV) : 0.f;                                       \
    a_p  += (PV);                                                     \
    sw += BGET5((C)+32) - BGET5((C)+1);                               \
  } while (0)

#define UB(W,J) ((int)(((W) >> (8*(J))) & 7u))            // u byte (0..4)
#define VB(W,J) ((int)(((W) >> (8*(J))) & 3u))            // v+1 byte (0..2)

#define SHFLS(DX, DY, SX, SY)                               \
    DX##1x = __shfl_up(SX, 1, 64);  DY##1y = __shfl_up(SY, 1, 64);  \
    DX##0x = __shfl_up(SX, 2, 64);  DY##0y = __shfl_up(SY, 2, 64);  \
    DX##3x = __shfl_down(SX, 1, 64); DY##3y = __shfl_down(SY, 1, 64); \
    DX##4x = __shfl_down(SX, 2, 64); DY##4y = __shfl_down(SY, 2, 64)

// fused body (2 rows), rolling SPL/SPH registers; E = ys & 15 in {0,2,...,14}.
template<int E>
__device__ __forceinline__ void fused_rows(uint4 B0, uint4 B1, uint4 B2,
                                           const float* __restrict__ prow,
                                           int lane,
                                           float& a_c, float& a_pt, float& a_p) {
  // two-chain 31-tap init
  unsigned cLoA = 0u, cHiA = 0u, cLoB = 0u, cHiB = 0u;
#pragma unroll
  for (int j = -15; j <= 13; j += 2) {
    unsigned ba_ = BYTE48(j + 16 + E);
    unsigned bb_ = BYTE48(j + 17 + E);
    cLoA += SPL(ba_); cHiA += SPH(ba_);
    cLoB += SPL(bb_); cHiB += SPH(bb_);
  }
  { unsigned bl_ = BYTE48(31 + E); cLoA += SPL(bl_); cHiA += SPH(bl_); }
  unsigned cLo = cLoA + cLoB, cHi = cHiA + cHiB;

  unsigned bm = BYTE48(15 + E);   // row ys-1 (OOB auto-zero via zeroed blocks)
  unsigned bz = BYTE48(16 + E);   // row ys
  unsigned bq = BYTE48(17 + E);   // row ys+1
  unsigned smLo = SPL(bm), smHi = SPH(bm);
  unsigned szLo = SPL(bz), szHi = SPH(bz);
  unsigned sqLo = SPL(bq), sqHi = SPH(bq);

  // row 0: packed word + shfls + pred
  unsigned w2x = cLo | (szLo << 5) | (smLo << 6) | (sqLo << 7);
  unsigned w2y = cHi | (szHi << 5) | (smHi << 6) | (sqHi << 7);
  unsigned w1x, w0x, w3x, w4x, w1y, w0y, w3y, w4y;
  SHFLS(w, w, w2x, w2y);
  float4 pA = *(const float4*)prow;
  float4 pB = *(const float4*)(prow + 4);

#pragma unroll
  for (int j = 0; j < 2; ++j) {
    // ---- current-row own derived (from rolling regs, BEFORE roll) ----
    unsigned uLo = smLo + sqLo + 2u * szLo;
    unsigned uHi = smHi + sqHi + 2u * szHi;
    unsigned vLo = (sqLo + 0x01010101u) - smLo;
    unsigned vHi = (sqHi + 0x01010101u) - smHi;
    unsigned bzCur = bz;
    unsigned cw2x = w2x, cw2y = w2y;

    // ---- prefetch next row (pred + roll + window shfls) ----
    unsigned nw2x = 0u, nw2y = 0u;
    unsigned nw1x = 0u, nw0x = 0u, nw3x = 0u, nw4x = 0u;
    unsigned nw1y = 0u, nw0y = 0u, nw3y = 0u, nw4y = 0u;
    float4 nA = make_float4(0, 0, 0, 0), nB = make_float4(0, 0, 0, 0);
    if (j < 1) {
      nA = *(const float4*)(prow + WW);
      nB = *(const float4*)(prow + WW + 4);
      unsigned ba = BYTE48(32 + E + j);   // row ys+j+16 enters box
      unsigned bs = BYTE48(1 + E + j);    // row ys+j-15 leaves box
      cLo += SPL(ba) - SPL(bs);
      cHi += SPH(ba) - SPH(bs);
      smLo = szLo; smHi = szHi; szLo = sqLo; szHi = sqHi; bz = bq;
      bq = BYTE48(18 + E + j);
      sqLo = SPL(bq); sqHi = SPH(bq);
      nw2x = cLo | (szLo << 5) | (smLo << 6) | (sqLo << 7);
      nw2y = cHi | (szHi << 5) | (smHi << 6) | (sqHi << 7);
      SHFLS(nw, nw, nw2x, nw2y);
    }

    // ---- current row: mask edges, then STEP ----
    unsigned c0x = (lane < 2)  ? 0u : w0x, c0y = (lane < 2)  ? 0u : w0y;
    unsigned c1x = (lane < 1)  ? 0u : w1x, c1y = (lane < 1)  ? 0u : w1y;
    unsigned c2x = cw2x,                   c2y = cw2y;
    unsigned c3x = (lane > 62) ? 0u : w3x, c3y = (lane > 62) ? 0u : w3y;
    unsigned c4x = (lane > 61) ? 0u : w4x, c4y = (lane > 61) ? 0u : w4y;

    int zm1 = (int)((c1y >> 29) & 1u), mm1 = (int)((c1y >> 30) & 1u), qm1 = (int)(c1y >> 31);
    int zp8 = (int)((c3x >> 5) & 1u),  mp8 = (int)((c3x >> 6) & 1u),  qp8 = (int)((c3x >> 7) & 1u);
    int uM1 = mm1 + 2*zm1 + qm1, vM1 = qm1 - mm1 + 1;
    int uP8 = mp8 + 2*zp8 + qp8, vP8 = qp8 - mp8 + 1;

    int u0=UB(uLo,0), u1=UB(uLo,1), u2c=UB(uLo,2), u3=UB(uLo,3);
    int u4=UB(uHi,0), u5=UB(uHi,1), u6=UB(uHi,2), u7=UB(uHi,3);
    int v0=VB(vLo,0), v1=VB(vLo,1), v2c=VB(vLo,2), v3=VB(vLo,3);
    int v4=VB(vHi,0), v5=VB(vHi,1), v6=VB(vHi,2), v7=VB(vHi,3);
    int t0=(int)((bzCur>>0)&1u), t1=(int)((bzCur>>1)&1u), t2=(int)((bzCur>>2)&1u), t3=(int)((bzCur>>3)&1u);
    int t4=(int)((bzCur>>4)&1u), t5=(int)((bzCur>>5)&1u), t6=(int)((bzCur>>6)&1u), t7=(int)((bzCur>>7)&1u);

    unsigned p0 = (c0x & 0x1F1F1F1Fu) + (c0y & 0x1F1F1F1Fu)
                + (c1x & 0x1F1F1F1Fu) + (c1y & 0x1F1F1F1Fu)
                + (c2x & 0x1F1F1F1Fu) + (c2y & 0x1F1F1F1Fu)
                + (c3x & 0x1F1F1F1Fu) + (c3y & 0x1F1F1F1Fu);
    int sw = sum4b(p0) - (int)(c0x & 0x1Fu);

    STEP(0, uM1, u1,  vM1, v0,  v1,  t0, pA.x);
    STEP(1, u0,  u2c, v0,  v1,  v2c, t1, pA.y);
    STEP(2, u1,  u3,  v1,  v2c, v3,  t2, pA.z);
    STEP(3, u2c, u4,  v2c, v3,  v4,  t3, pA.w);
    STEP(4, u3,  u5,  v3,  v4,  v5,  t4, pB.x);
    STEP(5, u4,  u6,  v4,  v5,  v6,  t5, pB.y);
    STEP(6, u5,  u7,  v5,  v6,  v7,  t6, pB.z);
    STEP(7, u6,  uP8, v6,  v7,  vP8, t7, pB.w);

    // ---- rotate pipeline ----
    w2x = nw2x; w2y = nw2y;
    w0x = nw0x; w0y = nw0y; w1x = nw1x; w1y = nw1y;
    w3x = nw3x; w3y = nw3y; w4x = nw4x; w4y = nw4y;
    pA = nA; pB = nB;
    prow += WW;
  }
}

// fully fused: wave = 64 byte-cols x 2 rows (4096 blocks -> max TLP);
// NO threadfence / in-kernel final (R20 lesson: device fences cost ~400us).
__global__ __launch_bounds__(256) void k_fused(const float* __restrict__ pred,
                                               const unsigned char* __restrict__ bitsT,
                                               double* __restrict__ acc) {
  __shared__ float s_red[4][3];
  // XCD grouping: XCD x (= blockIdx%8) handles wids x*512..x*512+511 = 8 images
  int wid = (blockIdx.x & 7) * 512 + (blockIdx.x >> 3);   // bijective, 4096 blocks
  int b   = wid >> 6;
  int tid = threadIdx.x;
  int wv  = tid >> 6, lane = tid & 63;
  int ys  = (wid & 63) * 8 + wv * 2;   // wave's 2-row segment base
  int s2  = ys >> 4;                   // 16-row block index

  uint4 B0 = make_uint4(0u,0u,0u,0u), B2 = make_uint4(0u,0u,0u,0u);
  if (s2 >= 1)  B0 = *(const uint4*)(bitsT + (((size_t)(b * 32 + s2 - 1) * 64 + lane) << 4));
  uint4 B1      = *(const uint4*)(bitsT + (((size_t)(b * 32 + s2)     * 64 + lane) << 4));
  if (s2 <= 30) B2 = *(const uint4*)(bitsT + (((size_t)(b * 32 + s2 + 1) * 64 + lane) << 4));

  const float* prow = pred + (size_t)b * HWQ + (size_t)ys * WW + lane * 8;

  float a_c = 0.f, a_pt = 0.f, a_p = 0.f;
  switch ((ys >> 1) & 7) {
    case 0: fused_rows<0>(B0, B1, B2, prow, lane, a_c, a_pt, a_p);  break;
    case 1: fused_rows<2>(B0, B1, B2, prow, lane, a_c, a_pt, a_p);  break;
    case 2: fused_rows<4>(B0, B1, B2, prow, lane, a_c, a_pt, a_p);  break;
    case 3: fused_rows<6>(B0, B1, B2, prow, lane, a_c, a_pt, a_p);  break;
    case 4: fused_rows<8>(B0, B1, B2, prow, lane, a_c, a_pt, a_p);  break;
    case 5: fused_rows<10>(B0, B1, B2, prow, lane, a_c, a_pt, a_p); break;
    case 6: fused_rows<12>(B0, B1, B2, prow, lane, a_c, a_pt, a_p); break;
    default: fused_rows<14>(B0, B1, B2, prow, lane, a_c, a_pt, a_p); break;
  }

  a_c = wredf(a_c); a_pt = wredf(a_pt); a_p = wredf(a_p);
  if (lane == 0) { s_red[wv][0] = a_c; s_red[wv][1] = a_pt; s_red[wv][2] = a_p; }
  __syncthreads();
  if (tid == 0) {
    float rc = 0, rpt = 0, rp = 0;
    for (int w = 0; w < 4; ++w) { rc += s_red[w][0]; rpt += s_red[w][1]; rp += s_red[w][2]; }
    atomicAdd(&acc[wid & 63],     (double)rc);
    atomicAdd(&acc[64 + 8*b + 0], (double)rpt);
    atomicAdd(&acc[64 + 8*b + 1], (double)rp);
  }
}

__global__ void k_final(const double* __restrict__ acc, const double* __restrict__ tpart,
                        float* __restrict__ out) {
  int t = threadIdx.x;  // 64 threads = 1 wave; t = image index
  double cs = acc[t];
  double TP = acc[64 + 8*t], Ps = acc[64 + 8*t + 1];
  double Ts = 0.0;
  for (int j = 0; j < 16; ++j) Ts += tpart[t * 16 + j];   // 16 k_bitsT blocks per image
  double FP = Ps - TP, FN = Ts - TP;
  double tv = (TP + 1e-6) / (TP + 0.3 * FP + 0.7 * FN + 1e-6);
  double om = 1.0 - tv;
  if (om < 0.0) om = 0.0;
  double term = pow(om, 1.0 / 1.33);
#pragma unroll
  for (int o = 32; o > 0; o >>= 1) {
    cs   += __shfl_down(cs, o, 64);
    term += __shfl_down(term, o, 64);
  }
  if (t == 0) {
    double ftl = term / 64.0;
    double n = (double)NTOT;
    out[0] = (float)(ftl - 0.6931471805599453 * cs / n);  // bce = -ln2 * log2(q)
  }
}

extern "C" void kernel_launch(void* const* d_in, const int* in_sizes, int n_in,
                              void* d_out, int out_size, void* d_ws, size_t ws_size,
                              hipStream_t stream) {
  (void)in_sizes; (void)n_in; (void)out_size; (void)ws_size;
  const float* pred = (const float*)d_in[0];
  const float* tgt  = (const float*)d_in[1];
  unsigned char* bitsT = (unsigned char*)d_ws;
  double* acc = (double*)((char*)d_ws + BITS_BYTES);
  double* tpart = acc + ACC_MAIN_DOUBLES;

  k_bitsT<<<1024, 256, 0, stream>>>(tgt, bitsT, acc, tpart);
  k_fused<<<NFBLK, 256, 0, stream>>>(pred, bitsT, acc);
  k_final<<<1, 64, 0, stream>>>(acc, tpart, (float*)d_out);
}

// Round 22
// 42.613 us; speedup vs baseline: 10.4833x; 1.0690x over previous
//
#include <hip/hip_runtime.h>
#include <math.h>

#define BB 64
#define HH 512
#define WW 512
#define HWQ (HH*WW)
#define NTOT ((size_t)BB*HWQ)

// ws layout:
//  [0, 2MB)   : TRANSPOSED bitmask: byte for (b, bytecol bc, row r) at
//               bitsT[((b*32 + (r>>4))*64 + bc)*16 + (r&15)]
//  then doubles:
//   [0..63]      a_c slots (k_fused atomics; zeroed by k_bitsT block 0)
//   [64+8b+0,1]  TP_b, sumP_b (k_fused atomics; zeroed by k_bitsT block 0)
//   [576+blk]    k_bitsT per-block t-count partials (plain stores)
#define BITS_BYTES (NTOT / 8)
#define ACC_MAIN_DOUBLES 576
#define NFBLK 2048

#define FU(X) (__float_as_uint(X))

// target f32 -> transposed bitmask + per-block t-count. 1024 blocks. (R14 proven)
__global__ __launch_bounds__(256) void k_bitsT(const float* __restrict__ tgt,
                                               unsigned char* __restrict__ bitsT,
                                               double* __restrict__ accz,
                                               double* __restrict__ tpart) {
  if (blockIdx.x == 0) {
    for (int i = threadIdx.x; i < ACC_MAIN_DOUBLES; i += 256) accz[i] = 0.0;
  }
  int tid  = threadIdx.x;
  int bc   = tid & 63;
  int unit = blockIdx.x * 4 + (tid >> 6);   // 4096 units = 64 img x 64 rowgroups(8)
  int b    = unit >> 6;
  int rg   = unit & 63;
  int r0   = rg * 8;
  const float* timg = tgt + (size_t)b * HWQ;
  unsigned wlo = 0u, whi = 0u;
#pragma unroll
  for (int j = 0; j < 8; ++j) {
    const float* rp = timg + (size_t)(r0 + j) * WW + bc * 8;
    float4 a = *(const float4*)rp;
    float4 c = *(const float4*)(rp + 4);
    unsigned by = ((FU(a.x) >> 29) & 1u)        | (((FU(a.y) >> 29) & 1u) << 1)
                | (((FU(a.z) >> 29) & 1u) << 2) | (((FU(a.w) >> 29) & 1u) << 3)
                | (((FU(c.x) >> 29) & 1u) << 4) | (((FU(c.y) >> 29) & 1u) << 5)
                | (((FU(c.z) >> 29) & 1u) << 6) | (((FU(c.w) >> 29) & 1u) << 7);
    if (j < 4) wlo |= by << (8 * j); else whi |= by << (8 * (j - 4));
  }
  int rb = r0 >> 4, off = r0 & 15;
  *(uint2*)(bitsT + (((size_t)(b * 32 + rb) * 64 + bc) << 4) + off) = make_uint2(wlo, whi);

  int cnt = __popc(wlo) + __popc(whi);
#pragma unroll
  for (int o = 32; o > 0; o >>= 1) cnt += __shfl_down(cnt, o, 64);
  __shared__ int s_t[4];
  int wv = tid >> 6, lane = tid & 63;
  if (lane == 0) s_t[wv] = cnt;
  __syncthreads();
  if (tid == 0) tpart[blockIdx.x] = (double)(s_t[0] + s_t[1] + s_t[2] + s_t[3]);
}

// nibble -> byte-lane spread (bit j of nibble -> byte j)
#define SPL(B) ((((B) & 0xFu) * 0x00204081u) & 0x01010101u)
#define SPH(B) ((((B) >> 4)   * 0x00204081u) & 0x01010101u)

// byte K (0..47) of the 3-block register window B0,B1,B2 (K compile-time)
#define W48(K) ((K)<16 ? (((K)&15)<8 ? (((K)&15)<4?B0.x:B0.y) : (((K)&15)<12?B0.z:B0.w)) \
              : (K)<32 ? (((K)&15)<8 ? (((K)&15)<4?B1.x:B1.y) : (((K)&15)<12?B1.z:B1.w)) \
                       : (((K)&15)<8 ? (((K)&15)<4?B2.x:B2.y) : (((K)&15)<12?B2.z:B2.w)))
#define BYTE48(K) ((W48(K) >> (((K)&3)*8)) & 0xFFu)

__device__ inline float wredf(float v) {
#pragma unroll
  for (int o = 32; o > 0; o >>= 1) v += __shfl_down(v, o, 64);
  return v;
}

__device__ inline int sum4b(unsigned x) {     // sum of the 4 bytes
  unsigned t = (x & 0x00FF00FFu) + ((x >> 8) & 0x00FF00FFu);
  return (int)((t + (t >> 16)) & 0xFFFFu);
}

// window byte I (0..39) <-> col x0-16+I ; I compile-time -> folds to one bfe
#define VTW(I) ((I) < 8  ? (((I)&7) < 4 ? c0x : c0y) : \
                (I) < 16 ? (((I)&7) < 4 ? c1x : c1y) : \
                (I) < 24 ? (((I)&7) < 4 ? c2x : c2y) : \
                (I) < 32 ? (((I)&7) < 4 ? c3x : c3y) : \
                           (((I)&7) < 4 ? c4x : c4y))
#define BGET5(I) ((int)((VTW(I) >> (((I)&3)*8)) & 31u))   // 5-bit vsum field

// one output column (identical math to R8..R21, which passed)
#define STEP(C, UM, UP, VM, VC, VP, TCI, PV) do {                     \
    int gx = (UP) - (UM);                                             \
    int gy = (VM) + 2*(VC) + (VP) - 4;                                \
    float tb = __builtin_amdgcn_sqrtf((float)(gx*gx + gy*gy) + 1e-12f); \
    float qq = (TCI) ? (PV) : 1.f - (PV);                             \
    float lg = __log2f(qq);                                           \
    int   di = (TCI) ? (961 - sw) : sw;                               \
    float wgt = fmaf(5.f, tb, fmaf(1.5608741e-3f, (float)di, 0.8f));  \
    a_c = fmaf(wgt, lg, a_c);                                         \
    a_pt += (TCI) ? (PV) : 0.f;                                       \
    a_p  += (PV);                                                     \
    sw += BGET5((C)+32) - BGET5((C)+1);                               \
  } while (0)

#define UB(W,J) ((int)(((W) >> (8*(J))) & 7u))            // u byte (0..4)
#define VB(W,J) ((int)(((W) >> (8*(J))) & 3u))            // v+1 byte (0..2)

#define SHFLS(DX, DY, SX, SY)                               \
    DX##1x = __shfl_up(SX, 1, 64);  DY##1y = __shfl_up(SY, 1, 64);  \
    DX##0x = __shfl_up(SX, 2, 64);  DY##0y = __shfl_up(SY, 2, 64);  \
    DX##3x = __shfl_down(SX, 1, 64); DY##3y = __shfl_down(SY, 1, 64); \
    DX##4x = __shfl_down(SX, 2, 64); DY##4y = __shfl_down(SY, 2, 64)

// fused body (4 rows), rolling SPL/SPH registers; E = wv*4 in {0,4,8,12}.
template<int E>
__device__ __forceinline__ void fused_rows(uint4 B0, uint4 B1, uint4 B2,
                                           const float* __restrict__ prow,
                                           int lane,
                                           float& a_c, float& a_pt, float& a_p) {
  // two-chain 31-tap init
  unsigned cLoA = 0u, cHiA = 0u, cLoB = 0u, cHiB = 0u;
#pragma unroll
  for (int j = -15; j <= 13; j += 2) {
    unsigned ba_ = BYTE48(j + 16 + E);
    unsigned bb_ = BYTE48(j + 17 + E);
    cLoA += SPL(ba_); cHiA += SPH(ba_);
    cLoB += SPL(bb_); cHiB += SPH(bb_);
  }
  { unsigned bl_ = BYTE48(31 + E); cLoA += SPL(bl_); cHiA += SPH(bl_); }
  unsigned cLo = cLoA + cLoB, cHi = cHiA + cHiB;

  unsigned bm = BYTE48(15 + E);   // row ys-1 (OOB auto-zero via zeroed blocks)
  unsigned bz = BYTE48(16 + E);   // row ys
  unsigned bq = BYTE48(17 + E);   // row ys+1
  unsigned smLo = SPL(bm), smHi = SPH(bm);
  unsigned szLo = SPL(bz), szHi = SPH(bz);
  unsigned sqLo = SPL(bq), sqHi = SPH(bq);

  // row 0: packed word + shfls + pred
  unsigned w2x = cLo | (szLo << 5) | (smLo << 6) | (sqLo << 7);
  unsigned w2y = cHi | (szHi << 5) | (smHi << 6) | (sqHi << 7);
  unsigned w1x, w0x, w3x, w4x, w1y, w0y, w3y, w4y;
  SHFLS(w, w, w2x, w2y);
  float4 pA = *(const float4*)prow;
  float4 pB = *(const float4*)(prow + 4);

#pragma unroll
  for (int j = 0; j < 4; ++j) {
    // ---- current-row own derived (from rolling regs, BEFORE roll) ----
    unsigned uLo = smLo + sqLo + 2u * szLo;
    unsigned uHi = smHi + sqHi + 2u * szHi;
    unsigned vLo = (sqLo + 0x01010101u) - smLo;
    unsigned vHi = (sqHi + 0x01010101u) - smHi;
    unsigned bzCur = bz;
    unsigned cw2x = w2x, cw2y = w2y;

    // ---- prefetch next row (pred + roll + window shfls) ----
    unsigned nw2x = 0u, nw2y = 0u;
    unsigned nw1x = 0u, nw0x = 0u, nw3x = 0u, nw4x = 0u;
    unsigned nw1y = 0u, nw0y = 0u, nw3y = 0u, nw4y = 0u;
    float4 nA = make_float4(0, 0, 0, 0), nB = make_float4(0, 0, 0, 0);
    if (j < 3) {
      nA = *(const float4*)(prow + WW);
      nB = *(const float4*)(prow + WW + 4);
      unsigned ba = BYTE48(32 + E + j);   // row ys+j+16 enters box
      unsigned bs = BYTE48(1 + E + j);    // row ys+j-15 leaves box
      cLo += SPL(ba) - SPL(bs);
      cHi += SPH(ba) - SPH(bs);
      smLo = szLo; smHi = szHi; szLo = sqLo; szHi = sqHi; bz = bq;
      bq = BYTE48(18 + E + j);
      sqLo = SPL(bq); sqHi = SPH(bq);
      nw2x = cLo | (szLo << 5) | (smLo << 6) | (sqLo << 7);
      nw2y = cHi | (szHi << 5) | (smHi << 6) | (sqHi << 7);
      SHFLS(nw, nw, nw2x, nw2y);
    }

    // ---- current row: mask edges, then STEP ----
    unsigned c0x = (lane < 2)  ? 0u : w0x, c0y = (lane < 2)  ? 0u : w0y;
    unsigned c1x = (lane < 1)  ? 0u : w1x, c1y = (lane < 1)  ? 0u : w1y;
    unsigned c2x = cw2x,                   c2y = cw2y;
    unsigned c3x = (lane > 62) ? 0u : w3x, c3y = (lane > 62) ? 0u : w3y;
    unsigned c4x = (lane > 61) ? 0u : w4x, c4y = (lane > 61) ? 0u : w4y;

    int zm1 = (int)((c1y >> 29) & 1u), mm1 = (int)((c1y >> 30) & 1u), qm1 = (int)(c1y >> 31);
    int zp8 = (int)((c3x >> 5) & 1u),  mp8 = (int)((c3x >> 6) & 1u),  qp8 = (int)((c3x >> 7) & 1u);
    int uM1 = mm1 + 2*zm1 + qm1, vM1 = qm1 - mm1 + 1;
    int uP8 = mp8 + 2*zp8 + qp8, vP8 = qp8 - mp8 + 1;

    int u0=UB(uLo,0), u1=UB(uLo,1), u2c=UB(uLo,2), u3=UB(uLo,3);
    int u4=UB(uHi,0), u5=UB(uHi,1), u6=UB(uHi,2), u7=UB(uHi,3);
    int v0=VB(vLo,0), v1=VB(vLo,1), v2c=VB(vLo,2), v3=VB(vLo,3);
    int v4=VB(vHi,0), v5=VB(vHi,1), v6=VB(vHi,2), v7=VB(vHi,3);
    int t0=(int)((bzCur>>0)&1u), t1=(int)((bzCur>>1)&1u), t2=(int)((bzCur>>2)&1u), t3=(int)((bzCur>>3)&1u);
    int t4=(int)((bzCur>>4)&1u), t5=(int)((bzCur>>5)&1u), t6=(int)((bzCur>>6)&1u), t7=(int)((bzCur>>7)&1u);

    unsigned p0 = (c0x & 0x1F1F1F1Fu) + (c0y & 0x1F1F1F1Fu)
                + (c1x & 0x1F1F1F1Fu) + (c1y & 0x1F1F1F1Fu)
                + (c2x & 0x1F1F1F1Fu) + (c2y & 0x1F1F1F1Fu)
                + (c3x & 0x1F1F1F1Fu) + (c3y & 0x1F1F1F1Fu);
    int sw = sum4b(p0) - (int)(c0x & 0x1Fu);

    STEP(0, uM1, u1,  vM1, v0,  v1,  t0, pA.x);
    STEP(1, u0,  u2c, v0,  v1,  v2c, t1, pA.y);
    STEP(2, u1,  u3,  v1,  v2c, v3,  t2, pA.z);
    STEP(3, u2c, u4,  v2c, v3,  v4,  t3, pA.w);
    STEP(4, u3,  u5,  v3,  v4,  v5,  t4, pB.x);
    STEP(5, u4,  u6,  v4,  v5,  v6,  t5, pB.y);
    STEP(6, u5,  u7,  v5,  v6,  v7,  t6, pB.z);
    STEP(7, u6,  uP8, v6,  v7,  vP8, t7, pB.w);

    // ---- rotate pipeline ----
    w2x = nw2x; w2y = nw2y;
    w0x = nw0x; w0y = nw0y; w1x = nw1x; w1y = nw1y;
    w3x = nw3x; w3y = nw3y; w4x = nw4x; w4y = nw4y;
    pA = nA; pB = nB;
    prow += WW;
  }
}

// fully fused: wave = 64 byte-cols x 4 rows (2048 blocks, R17-proven geometry)
// + R21 rolling-spread row body. No fences (R20 lesson).
__global__ __launch_bounds__(256) void k_fused(const float* __restrict__ pred,
                                               const unsigned char* __restrict__ bitsT,
                                               double* __restrict__ acc) {
  __shared__ float s_red[4][3];
  // XCD grouping: XCD x (= blockIdx%8) handles wids x*256..x*256+255 = 8 images
  int wid = (blockIdx.x & 7) * 256 + (blockIdx.x >> 3);   // bijective, 2048 blocks
  int b   = wid >> 5;
  int tid = threadIdx.x;
  int wv  = tid >> 6, lane = tid & 63;
  int s2  = wid & 31;              // 16-row block index
  int ys  = s2 * 16 + wv * 4;      // wave's 4-row segment base; E = wv*4

  uint4 B0 = make_uint4(0u,0u,0u,0u), B2 = make_uint4(0u,0u,0u,0u);
  if (s2 >= 1)  B0 = *(const uint4*)(bitsT + (((size_t)(b * 32 + s2 - 1) * 64 + lane) << 4));
  uint4 B1      = *(const uint4*)(bitsT + (((size_t)(b * 32 + s2)     * 64 + lane) << 4));
  if (s2 <= 30) B2 = *(const uint4*)(bitsT + (((size_t)(b * 32 + s2 + 1) * 64 + lane) << 4));

  const float* prow = pred + (size_t)b * HWQ + (size_t)ys * WW + lane * 8;

  float a_c = 0.f, a_pt = 0.f, a_p = 0.f;
  switch (wv) {
    case 0:  fused_rows<0>(B0, B1, B2, prow, lane, a_c, a_pt, a_p);  break;
    case 1:  fused_rows<4>(B0, B1, B2, prow, lane, a_c, a_pt, a_p);  break;
    case 2:  fused_rows<8>(B0, B1, B2, prow, lane, a_c, a_pt, a_p);  break;
    default: fused_rows<12>(B0, B1, B2, prow, lane, a_c, a_pt, a_p); break;
  }

  a_c = wredf(a_c); a_pt = wredf(a_pt); a_p = wredf(a_p);
  if (lane == 0) { s_red[wv][0] = a_c; s_red[wv][1] = a_pt; s_red[wv][2] = a_p; }
  __syncthreads();
  if (tid == 0) {
    float rc = 0, rpt = 0, rp = 0;
    for (int w = 0; w < 4; ++w) { rc += s_red[w][0]; rpt += s_red[w][1]; rp += s_red[w][2]; }
    atomicAdd(&acc[wid & 63],     (double)rc);
    atomicAdd(&acc[64 + 8*b + 0], (double)rpt);
    atomicAdd(&acc[64 + 8*b + 1], (double)rp);
  }
}

__global__ void k_final(const double* __restrict__ acc, const double* __restrict__ tpart,
                        float* __restrict__ out) {
  int t = threadIdx.x;  // 64 threads = 1 wave; t = image index
  double cs = acc[t];
  double TP = acc[64 + 8*t], Ps = acc[64 + 8*t + 1];
  double Ts = 0.0;
  for (int j = 0; j < 16; ++j) Ts += tpart[t * 16 + j];   // 16 k_bitsT blocks per image
  double FP = Ps - TP, FN = Ts - TP;
  double tv = (TP + 1e-6) / (TP + 0.3 * FP + 0.7 * FN + 1e-6);
  double om = 1.0 - tv;
  if (om < 0.0) om = 0.0;
  double term = pow(om, 1.0 / 1.33);
#pragma unroll
  for (int o = 32; o > 0; o >>= 1) {
    cs   += __shfl_down(cs, o, 64);
    term += __shfl_down(term, o, 64);
  }
  if (t == 0) {
    double ftl = term / 64.0;
    double n = (double)NTOT;
    out[0] = (float)(ftl - 0.6931471805599453 * cs / n);  // bce = -ln2 * log2(q)
  }
}

extern "C" void kernel_launch(void* const* d_in, const int* in_sizes, int n_in,
                              void* d_out, int out_size, void* d_ws, size_t ws_size,
                              hipStream_t stream) {
  (void)in_sizes; (void)n_in; (void)out_size; (void)ws_size;
  const float* pred = (const float*)d_in[0];
  const float* tgt  = (const float*)d_in[1];
  unsigned char* bitsT = (unsigned char*)d_ws;
  double* acc = (double*)((char*)d_ws + BITS_BYTES);
  double* tpart = acc + ACC_MAIN_DOUBLES;

  k_bitsT<<<1024, 256, 0, stream>>>(tgt, bitsT, acc, tpart);
  k_fused<<<NFBLK, 256, 0, stream>>>(pred, bitsT, acc);
  k_final<<<1, 64, 0, stream>>>(acc, tpart, (float*)d_out);
}